// Round 3
// baseline (393.206 us; speedup 1.0000x reference)
//
#include <hip/hip_runtime.h>
#include <hip/hip_fp16.h>

#define NU 50000
#define NP 50000
#define NN 100000
#define NE 600000
#define H  128
#define O  16

typedef __attribute__((ext_vector_type(8))) _Float16 half8;
typedef __attribute__((ext_vector_type(4))) _Float16 h4v;
typedef __attribute__((ext_vector_type(4))) float f32x4;

// ---------------------------------------------------------------- fused weight prep + cnt zero + epack pad
// idx < 75776: 2-term f16 weight decomposition (x16 scaled)
// idx >= 75776: zero cnt[NN]; zero 8 pad entries at epack[NE..NE+8)
__global__ void k_prep(const float* __restrict__ Wu, const float* __restrict__ Wp,
                       const float* __restrict__ W1, const float* __restrict__ W2,
                       const float* __restrict__ W3, const float* __restrict__ Wo,
                       __half* __restrict__ whU, __half* __restrict__ wlU,
                       __half* __restrict__ whP, __half* __restrict__ wlP,
                       __half* __restrict__ wh1, __half* __restrict__ wl1,
                       __half* __restrict__ wh2, __half* __restrict__ wl2,
                       __half* __restrict__ wh3, __half* __restrict__ wl3,
                       __half* __restrict__ whO, __half* __restrict__ wlO,
                       int* __restrict__ cnt, int2* __restrict__ epack) {
    int idx = blockIdx.x * blockDim.x + threadIdx.x;
    if (idx >= 75776) {
        int i = idx - 75776;
        if (i < NN) cnt[i] = 0;
        else if (i < NN + 8) { int2 z; z.x = 0; z.y = 0; epack[NE + (i - NN)] = z; }
        return;
    }
    const float* W; __half *Wh, *Wl; int K, KPAD, NC;
    if      (idx <  8192) {              W = Wu; Wh = whU; Wl = wlU; K =  64; KPAD =  64; NC = 128; }
    else if (idx < 24576) { idx -=  8192; W = Wp; Wh = whP; Wl = wlP; K = 100; KPAD = 128; NC = 128; }
    else if (idx < 40960) { idx -= 24576; W = W1; Wh = wh1; Wl = wl1; K = 128; KPAD = 128; NC = 128; }
    else if (idx < 57344) { idx -= 40960; W = W2; Wh = wh2; Wl = wl2; K = 128; KPAD = 128; NC = 128; }
    else if (idx < 73728) { idx -= 57344; W = W3; Wh = wh3; Wl = wl3; K = 128; KPAD = 128; NC = 128; }
    else                  { idx -= 73728; W = Wo; Wh = whO; Wl = wlO; K = 128; KPAD = 128; NC =  16; }
    int n = idx / KPAD, k = idx - n * KPAD;
    float x = (k < K) ? W[k * NC + n] * 16.0f : 0.0f;
    __half h = __float2half_rn(x);
    __half l = __float2half_rn(x - __half2float(h));
    Wh[idx] = h; Wl[idx] = l;
}

// ---------------------------------------------------------------- degree count + rank
__global__ void k_count(const int* __restrict__ dst, int* __restrict__ cnt,
                        int* __restrict__ rank, int E) {
    int e = blockIdx.x * blockDim.x + threadIdx.x;
    if (e < E) rank[e] = atomicAdd(&cnt[dst[e]], 1);
}

// ---------------------------------------------------------------- exclusive scan (2 kernels;
// the block-offset fixup is folded into the consumers: final = offs[i] + bsums[i>>10])
#define SCAN_TPB 256
#define SCAN_VPT 4
#define SCAN_CHUNK (SCAN_TPB * SCAN_VPT)   // 1024 -> consumers use >>10

__global__ void k_scan1(const int* __restrict__ in, int* __restrict__ out,
                        int* __restrict__ bsums, float* __restrict__ dinv, int n) {
    __shared__ int sh[SCAN_TPB];
    int t = threadIdx.x, b = blockIdx.x;
    int base = b * SCAN_CHUNK + t * SCAN_VPT;
    int v[SCAN_VPT]; int s = 0;
#pragma unroll
    for (int i = 0; i < SCAN_VPT; i++) {
        int idx = base + i;
        v[i] = (idx < n) ? in[idx] : 0;
        if (idx < n) dinv[idx] = rsqrtf((float)(v[i] + 1));
        s += v[i];
    }
    sh[t] = s; __syncthreads();
    for (int off = 1; off < SCAN_TPB; off <<= 1) {
        int x = (t >= off) ? sh[t - off] : 0;
        __syncthreads();
        sh[t] += x;
        __syncthreads();
    }
    int run = (t > 0) ? sh[t - 1] : 0;
    if (t == SCAN_TPB - 1) bsums[b] = sh[t];
#pragma unroll
    for (int i = 0; i < SCAN_VPT; i++) {
        int idx = base + i;
        if (idx < n) out[idx] = run;
        run += v[i];
    }
}

__global__ void k_scan2(int* __restrict__ bsums, int nb) {
    __shared__ int sh[128];
    int t = threadIdx.x;
    int v = (t < nb) ? bsums[t] : 0;
    sh[t] = v; __syncthreads();
    for (int off = 1; off < 128; off <<= 1) {
        int x = (t >= off) ? sh[t - off] : 0;
        __syncthreads();
        sh[t] += x;
        __syncthreads();
    }
    if (t < nb) bsums[t] = sh[t] - v;
}

// ---------------------------------------------------------------- CSR fill (atomic-free)
__global__ void k_fill(const int* __restrict__ src, const int* __restrict__ dst,
                       const int* __restrict__ offs, const int* __restrict__ bsums,
                       const int* __restrict__ rank, const float* __restrict__ dinv,
                       int2* __restrict__ epack, int E) {
    int e = blockIdx.x * blockDim.x + threadIdx.x;
    if (e < E) {
        int s = src[e], d = dst[e];
        int p = offs[d] + bsums[d >> 10] + rank[e];
        int2 r;
        r.x = s;
        r.y = __float_as_int(dinv[s] * dinv[d]);
        epack[p] = r;
    }
}

// ---------------------------------------------------------------- register-resident MFMA GEMM
// C[M,NOUT] = X[M,K] @ W (+bias), 2-term f16 (W pre-scaled x16, unscaled in
// epilogue). NO LDS, NO BARRIERS. One wave per (16-node group, MI*16-col group):
// 4x the wave count of the old 64-node layout -> latency hidden by TLP
// (old version: 8% occupancy, all pipes <5% busy). W frags re-read per wave
// (L2-resident, cheap); X rows read exactly once.
template <typename AT, int K, int KPAD, int MI, int NOUT, bool BIAS, bool F32OUT>
__device__ __forceinline__
void gemm_body(const AT* __restrict__ X,
               const __half* __restrict__ Wh, const __half* __restrict__ Wl,
               const float* __restrict__ bias, void* __restrict__ Cout,
               int M, int orow0, int vb) {
    constexpr int KS = KPAD / 32;
    constexpr int CSPLIT = NOUT / (16 * MI);
    const int tid  = threadIdx.x;
    const int wid  = tid >> 6, lane = tid & 63;
    const int lm   = lane & 15, q = lane >> 4;
    const int gw   = vb * 4 + wid;
    const int ng   = gw / CSPLIT;
    const int c0   = (gw % CSPLIT) * (MI * 16);
    const int NT16 = (M + 15) >> 4;
    if (ng >= NT16) return;
    const int node = ng * 16 + lm;

    // X fragment for this wave's 16 nodes (issued first: the HBM-latency path)
    half8 xf[KS];
    if (node < M) {
        if constexpr (sizeof(AT) == 2) {
#pragma unroll
            for (int ks = 0; ks < KS; ks++)
                xf[ks] = *(const half8*)((const __half*)X + (size_t)node * KPAD + ks * 32 + q * 8);
        } else {
            const float* xp = (const float*)X + (size_t)node * K;
#pragma unroll
            for (int ks = 0; ks < KS; ks++) {
                const int kb = ks * 32 + q * 8;
                if (kb + 8 <= K) {
                    float4 v0 = *(const float4*)(xp + kb);
                    float4 v1 = *(const float4*)(xp + kb + 4);
                    xf[ks][0] = (_Float16)v0.x; xf[ks][1] = (_Float16)v0.y;
                    xf[ks][2] = (_Float16)v0.z; xf[ks][3] = (_Float16)v0.w;
                    xf[ks][4] = (_Float16)v1.x; xf[ks][5] = (_Float16)v1.y;
                    xf[ks][6] = (_Float16)v1.z; xf[ks][7] = (_Float16)v1.w;
                } else if (kb + 4 <= K) {      // K=100 tail: one aligned float4
                    float4 v0 = *(const float4*)(xp + kb);
                    xf[ks][0] = (_Float16)v0.x; xf[ks][1] = (_Float16)v0.y;
                    xf[ks][2] = (_Float16)v0.z; xf[ks][3] = (_Float16)v0.w;
                    xf[ks][4] = (_Float16)0.0f; xf[ks][5] = (_Float16)0.0f;
                    xf[ks][6] = (_Float16)0.0f; xf[ks][7] = (_Float16)0.0f;
                } else {
#pragma unroll
                    for (int j = 0; j < 8; j++) xf[ks][j] = (_Float16)0.0f;
                }
            }
        }
    } else {
#pragma unroll
        for (int ks = 0; ks < KS; ks++)
#pragma unroll
            for (int j = 0; j < 8; j++) xf[ks][j] = (_Float16)0.0f;
    }

    f32x4 acc[MI];
#pragma unroll
    for (int mi = 0; mi < MI; mi++) acc[mi] = (f32x4)0.0f;

#pragma unroll
    for (int ks = 0; ks < KS; ks++) {
#pragma unroll
        for (int mi = 0; mi < MI; mi++) {
            const size_t b = (size_t)(c0 + mi * 16 + lm) * KPAD + ks * 32 + q * 8;
            half8 wh = *(const half8*)&Wh[b];
            half8 wl = *(const half8*)&Wl[b];
            acc[mi] = __builtin_amdgcn_mfma_f32_16x16x32_f16(wh, xf[ks], acc[mi], 0, 0, 0);
            acc[mi] = __builtin_amdgcn_mfma_f32_16x16x32_f16(wl, xf[ks], acc[mi], 0, 0, 0);
        }
    }

    if (node >= M) return;
#pragma unroll
    for (int mi = 0; mi < MI; mi++) {
        const int cb = c0 + mi * 16 + q * 4;
        float4 bv = BIAS ? *(const float4*)&bias[cb] : make_float4(0.f, 0.f, 0.f, 0.f);
        float v0 = fmaf(acc[mi][0], 0.0625f, bv.x);
        float v1 = fmaf(acc[mi][1], 0.0625f, bv.y);
        float v2 = fmaf(acc[mi][2], 0.0625f, bv.z);
        float v3 = fmaf(acc[mi][3], 0.0625f, bv.w);
        if constexpr (F32OUT) {
            *(float4*)((float*)Cout + (size_t)(orow0 + node) * NOUT + cb) =
                make_float4(v0, v1, v2, v3);
        } else {
            __half2 h0 = __floats2half2_rn(v0, v1);
            __half2 h1 = __floats2half2_rn(v2, v3);
            uint2 o; o.x = *(unsigned*)&h0; o.y = *(unsigned*)&h1;
            *(uint2*)((__half*)Cout + (size_t)(orow0 + node) * NOUT + cb) = o;
        }
    }
}

template <typename AT, int K, int KPAD, int MI, int NOUT, bool BIAS, bool F32OUT>
__launch_bounds__(256)
__global__ void k_gemm_reg(const AT* __restrict__ X,
                           const __half* __restrict__ Wh, const __half* __restrict__ Wl,
                           const float* __restrict__ bias, void* __restrict__ Cout,
                           int M, int orow0) {
    gemm_body<AT, K, KPAD, MI, NOUT, BIAS, F32OUT>(X, Wh, Wl, bias, Cout, M, orow0, blockIdx.x);
}

// merged user+prod input transform (one launch, block-range split)
__launch_bounds__(256)
__global__ void k_gemm_inputs(const float* __restrict__ user, const float* __restrict__ prod,
                              const __half* __restrict__ whU, const __half* __restrict__ wlU,
                              const __half* __restrict__ whP, const __half* __restrict__ wlP,
                              const float* __restrict__ bu, const float* __restrict__ bp,
                              void* __restrict__ xA, int blkU) {
    if ((int)blockIdx.x < blkU)
        gemm_body<float,  64,  64, 4, 128, true, false>(user, whU, wlU, bu, xA, NU, 0, blockIdx.x);
    else
        gemm_body<float, 100, 128, 4, 128, true, false>(prod, whP, wlP, bp, xA, NP, NU, blockIdx.x - blkU);
}

// ---------------------------------------------------------------- CSR gather + bias + ReLU
// One WAVE per node, two 32-lane halves; lane owns features 4j..4j+3 (8B).
// Half h takes the CONTIGUOUS edge sub-range [e+4h, e+4h+4): the 4 epack loads
// are unclamped (epack padded by 8 zero entries) and contiguous -> compiler
// can merge to wide loads. One gather instr fetches two random rows (512B).
// Batches of 8 edges, predicated via zeroed weights; no serial tail.
__launch_bounds__(256)
__global__ void k_aggregate(const __half* __restrict__ y, const int* __restrict__ offs,
                            const int* __restrict__ bsums, const int2* __restrict__ epack,
                            const float* __restrict__ dinv, const float* __restrict__ bias,
                            __half* __restrict__ out) {
    const int node = __builtin_amdgcn_readfirstlane(blockIdx.x * 4 + (threadIdx.x >> 6));
    const int l = threadIdx.x & 63;
    const int h = l >> 5, j = l & 31;

    int e0 = offs[node] + bsums[node >> 10];
    int e1 = (node + 1 < NN) ? (offs[node + 1] + bsums[(node + 1) >> 10]) : NE;
    e0 = __builtin_amdgcn_readfirstlane(e0);
    e1 = __builtin_amdgcn_readfirstlane(e1);

    const h4v* y4 = (const h4v*)y;               // row stride = 32 (8B units)

    // self-loop row / bias / dinv issued before the edge loop (latency overlap)
    const float di2 = dinv[node] * dinv[node];
    h4v sv = y4[(size_t)node * 32 + j];
    float4 bv = *(const float4*)&bias[4 * j];

    f32x4 acc0 = (f32x4)0.f, acc1 = (f32x4)0.f, acc2 = (f32x4)0.f, acc3 = (f32x4)0.f;

    for (int e = e0; e < e1; e += 8) {
        const int eb = e + 4 * h;
        const int2* pe = epack + eb;
        int2 p0 = pe[0];                          // contiguous 32B per half
        int2 p1 = pe[1];
        int2 p2 = pe[2];
        int2 p3 = pe[3];
        float w0 = (eb + 0 < e1) ? __int_as_float(p0.y) : 0.f;
        float w1 = (eb + 1 < e1) ? __int_as_float(p1.y) : 0.f;
        float w2 = (eb + 2 < e1) ? __int_as_float(p2.y) : 0.f;
        float w3 = (eb + 3 < e1) ? __int_as_float(p3.y) : 0.f;
        h4v v0 = y4[(size_t)p0.x * 32 + j];      // 2 rows per gather instr
        h4v v1 = y4[(size_t)p1.x * 32 + j];
        h4v v2 = y4[(size_t)p2.x * 32 + j];
        h4v v3 = y4[(size_t)p3.x * 32 + j];
        acc0[0] = fmaf((float)v0[0], w0, acc0[0]); acc0[1] = fmaf((float)v0[1], w0, acc0[1]);
        acc0[2] = fmaf((float)v0[2], w0, acc0[2]); acc0[3] = fmaf((float)v0[3], w0, acc0[3]);
        acc1[0] = fmaf((float)v1[0], w1, acc1[0]); acc1[1] = fmaf((float)v1[1], w1, acc1[1]);
        acc1[2] = fmaf((float)v1[2], w1, acc1[2]); acc1[3] = fmaf((float)v1[3], w1, acc1[3]);
        acc2[0] = fmaf((float)v2[0], w2, acc2[0]); acc2[1] = fmaf((float)v2[1], w2, acc2[1]);
        acc2[2] = fmaf((float)v2[2], w2, acc2[2]); acc2[3] = fmaf((float)v2[3], w2, acc2[3]);
        acc3[0] = fmaf((float)v3[0], w3, acc3[0]); acc3[1] = fmaf((float)v3[1], w3, acc3[1]);
        acc3[2] = fmaf((float)v3[2], w3, acc3[2]); acc3[3] = fmaf((float)v3[3], w3, acc3[3]);
    }

    f32x4 s = (acc0 + acc1) + (acc2 + acc3);
    float t0 = s[0] + __shfl_xor(s[0], 32, 64);
    float t1 = s[1] + __shfl_xor(s[1], 32, 64);
    float t2 = s[2] + __shfl_xor(s[2], 32, 64);
    float t3 = s[3] + __shfl_xor(s[3], 32, 64);

    float r0 = fmaf((float)sv[0], di2, t0) + bv.x;
    float r1 = fmaf((float)sv[1], di2, t1) + bv.y;
    float r2 = fmaf((float)sv[2], di2, t2) + bv.z;
    float r3 = fmaf((float)sv[3], di2, t3) + bv.w;
    if (l < 32) {
        __half2 ha = __floats2half2_rn(fmaxf(r0, 0.f), fmaxf(r1, 0.f));
        __half2 hb = __floats2half2_rn(fmaxf(r2, 0.f), fmaxf(r3, 0.f));
        uint2 o; o.x = *(unsigned*)&ha; o.y = *(unsigned*)&hb;
        *(uint2*)(out + (size_t)node * H + 4 * j) = o;
    }
}

// ---------------------------------------------------------------- launch
extern "C" void kernel_launch(void* const* d_in, const int* in_sizes, int n_in,
                              void* d_out, int out_size, void* d_ws, size_t ws_size,
                              hipStream_t stream) {
    const float* user = (const float*)d_in[0];
    const float* prod = (const float*)d_in[1];
    const int*   eidx = (const int*)  d_in[2];
    const int*   edst = eidx + NE;
    const int*   esrc = eidx;
    const float* Wu = (const float*)d_in[3];
    const float* bu = (const float*)d_in[4];
    const float* Wp = (const float*)d_in[5];
    const float* bp = (const float*)d_in[6];
    const float* W1 = (const float*)d_in[7];
    const float* b1 = (const float*)d_in[8];
    const float* W2 = (const float*)d_in[9];
    const float* b2 = (const float*)d_in[10];
    const float* W3 = (const float*)d_in[11];
    const float* b3 = (const float*)d_in[12];
    const float* Wo = (const float*)d_in[13];
    const float* bo = (const float*)d_in[14];
    float* out = (float*)d_out;

    char* ws = (char*)d_ws;
    size_t p = 0;
    auto alloc = [&](size_t bytes) -> void* {
        void* r = ws + p;
        p += (bytes + 255) & ~(size_t)255;
        return r;
    };
    __half* xA   = (__half*)alloc((size_t)NN * H * 2);
    __half* xB   = (__half*)alloc((size_t)NN * H * 2);
    int*   cnt   = (int*)  alloc((size_t)NN * 4);
    int*   rank  = (int*)  alloc((size_t)NE * 4);
    int*   offs  = (int*)  alloc((size_t)(NN + 1) * 4);
    float* dinv  = (float*)alloc((size_t)NN * 4);
    int2*  epack = (int2*) alloc((size_t)(NE + 8) * 8);
    int*   bsums = (int*)  alloc(128 * 4);
    __half* whU = (__half*)alloc(128 * 64 * 2);
    __half* wlU = (__half*)alloc(128 * 64 * 2);
    __half* whP = (__half*)alloc(128 * 128 * 2);
    __half* wlP = (__half*)alloc(128 * 128 * 2);
    __half* wh1 = (__half*)alloc(128 * 128 * 2);
    __half* wl1 = (__half*)alloc(128 * 128 * 2);
    __half* wh2 = (__half*)alloc(128 * 128 * 2);
    __half* wl2 = (__half*)alloc(128 * 128 * 2);
    __half* wh3 = (__half*)alloc(128 * 128 * 2);
    __half* wl3 = (__half*)alloc(128 * 128 * 2);
    __half* whO = (__half*)alloc(16 * 128 * 2);
    __half* wlO = (__half*)alloc(16 * 128 * 2);

    const int NBLK = (NN + SCAN_CHUNK - 1) / SCAN_CHUNK;   // 98

    // weight prep + cnt zero + epack pad (one launch)
    k_prep<<<(75776 + NN + 8 + 255) / 256, 256, 0, stream>>>(
        Wu, Wp, W1, W2, W3, Wo,
        whU, wlU, whP, wlP, wh1, wl1, wh2, wl2, wh3, wl3, whO, wlO, cnt, epack);

    // graph structure
    k_count<<<(NE + 255) / 256, 256, 0, stream>>>(edst, cnt, rank, NE);
    k_scan1<<<NBLK, SCAN_TPB, 0, stream>>>(cnt, offs, bsums, dinv, NN);
    k_scan2<<<1, 128, 0, stream>>>(bsums, NBLK);
    k_fill <<<(NE + 255) / 256, 256, 0, stream>>>(esrc, edst, offs, bsums, rank, dinv,
                                                  epack, NE);

    // input feature transforms -> xA (fp16), merged into one launch
    // waves per side = NT16 * CSPLIT = 3125 * 2 = 6250 -> 1563 blocks each
    {
        constexpr int blkU = (3125 * 2 + 3) / 4;   // 1563
        constexpr int blkP = (3125 * 2 + 3) / 4;   // 1563
        k_gemm_inputs<<<blkU + blkP, 256, 0, stream>>>(
            user, prod, whU, wlU, whP, wlP, bu, bp, xA, blkU);
    }

    // hidden gemms: waves = 6250 * 2 = 12500 -> 3125 blocks
    const int blkG = (6250 * 2 + 3) / 4;   // 3125
    const int blkO = (6250 + 3) / 4;       // 1563 (head, MI=1 -> CSPLIT=1)

    // layer 1
    k_gemm_reg<__half, 128, 128, 4, 128, false, false><<<blkG, 256, 0, stream>>>(xA, wh1, wl1, nullptr, xB, NN, 0);
    k_aggregate<<<NN / 4, 256, 0, stream>>>(xB, offs, bsums, epack, dinv, b1, xA);
    // layer 2
    k_gemm_reg<__half, 128, 128, 4, 128, false, false><<<blkG, 256, 0, stream>>>(xA, wh2, wl2, nullptr, xB, NN, 0);
    k_aggregate<<<NN / 4, 256, 0, stream>>>(xB, offs, bsums, epack, dinv, b2, xA);
    // layer 3
    k_gemm_reg<__half, 128, 128, 4, 128, false, false><<<blkG, 256, 0, stream>>>(xA, wh3, wl3, nullptr, xB, NN, 0);
    k_aggregate<<<NN / 4, 256, 0, stream>>>(xB, offs, bsums, epack, dinv, b3, xA);

    // output head [NN,128] @ [128,16] + bo -> fp32 out
    k_gemm_reg<__half, 128, 128, 1, 16, true, true><<<blkO, 256, 0, stream>>>(xA, whO, wlO, bo, out, NN, 0);
}

// Round 6
// 295.560 us; speedup vs baseline: 1.3304x; 1.3304x over previous
//
#include <hip/hip_runtime.h>
#include <hip/hip_fp16.h>

#define NU 50000
#define NP 50000
#define NN 100000
#define NE 600000
#define H  128
#define O  16

typedef __attribute__((ext_vector_type(8))) _Float16 half8;
typedef __attribute__((ext_vector_type(4))) _Float16 h4v;
typedef __attribute__((ext_vector_type(4))) float f32x4;

// ---------------------------------------------------------------- fused weight prep + cnt zero + epack pad
__global__ void k_prep(const float* __restrict__ Wu, const float* __restrict__ Wp,
                       const float* __restrict__ W1, const float* __restrict__ W2,
                       const float* __restrict__ W3, const float* __restrict__ Wo,
                       __half* __restrict__ whU, __half* __restrict__ wlU,
                       __half* __restrict__ whP, __half* __restrict__ wlP,
                       __half* __restrict__ wh1, __half* __restrict__ wl1,
                       __half* __restrict__ wh2, __half* __restrict__ wl2,
                       __half* __restrict__ wh3, __half* __restrict__ wl3,
                       __half* __restrict__ whO, __half* __restrict__ wlO,
                       int* __restrict__ cnt, int2* __restrict__ epack) {
    int idx = blockIdx.x * blockDim.x + threadIdx.x;
    if (idx >= 75776) {
        int i = idx - 75776;
        if (i < NN) cnt[i] = 0;
        else if (i < NN + 8) { int2 z; z.x = 0; z.y = 0; epack[NE + (i - NN)] = z; }
        return;
    }
    const float* W; __half *Wh, *Wl; int K, KPAD, NC;
    if      (idx <  8192) {              W = Wu; Wh = whU; Wl = wlU; K =  64; KPAD =  64; NC = 128; }
    else if (idx < 24576) { idx -=  8192; W = Wp; Wh = whP; Wl = wlP; K = 100; KPAD = 128; NC = 128; }
    else if (idx < 40960) { idx -= 24576; W = W1; Wh = wh1; Wl = wl1; K = 128; KPAD = 128; NC = 128; }
    else if (idx < 57344) { idx -= 40960; W = W2; Wh = wh2; Wl = wl2; K = 128; KPAD = 128; NC = 128; }
    else if (idx < 73728) { idx -= 57344; W = W3; Wh = wh3; Wl = wl3; K = 128; KPAD = 128; NC = 128; }
    else                  { idx -= 73728; W = Wo; Wh = whO; Wl = wlO; K = 128; KPAD = 128; NC =  16; }
    int n = idx / KPAD, k = idx - n * KPAD;
    float x = (k < K) ? W[k * NC + n] * 16.0f : 0.0f;
    __half h = __float2half_rn(x);
    __half l = __float2half_rn(x - __half2float(h));
    Wh[idx] = h; Wl[idx] = l;
}

// ---------------------------------------------------------------- degree count + rank
__global__ void k_count(const int* __restrict__ dst, int* __restrict__ cnt,
                        int* __restrict__ rank, int E) {
    int e = blockIdx.x * blockDim.x + threadIdx.x;
    if (e < E) rank[e] = atomicAdd(&cnt[dst[e]], 1);
}

// ---------------------------------------------------------------- exclusive scan
#define SCAN_TPB 256
#define SCAN_VPT 4
#define SCAN_CHUNK (SCAN_TPB * SCAN_VPT)   // 1024 -> consumers use >>10

__global__ void k_scan1(const int* __restrict__ in, int* __restrict__ out,
                        int* __restrict__ bsums, float* __restrict__ dinv, int n) {
    __shared__ int sh[SCAN_TPB];
    int t = threadIdx.x, b = blockIdx.x;
    int base = b * SCAN_CHUNK + t * SCAN_VPT;
    int v[SCAN_VPT]; int s = 0;
#pragma unroll
    for (int i = 0; i < SCAN_VPT; i++) {
        int idx = base + i;
        v[i] = (idx < n) ? in[idx] : 0;
        if (idx < n) dinv[idx] = rsqrtf((float)(v[i] + 1));
        s += v[i];
    }
    sh[t] = s; __syncthreads();
    for (int off = 1; off < SCAN_TPB; off <<= 1) {
        int x = (t >= off) ? sh[t - off] : 0;
        __syncthreads();
        sh[t] += x;
        __syncthreads();
    }
    int run = (t > 0) ? sh[t - 1] : 0;
    if (t == SCAN_TPB - 1) bsums[b] = sh[t];
#pragma unroll
    for (int i = 0; i < SCAN_VPT; i++) {
        int idx = base + i;
        if (idx < n) out[idx] = run;
        run += v[i];
    }
}

__global__ void k_scan2(int* __restrict__ bsums, int nb) {
    __shared__ int sh[128];
    int t = threadIdx.x;
    int v = (t < nb) ? bsums[t] : 0;
    sh[t] = v; __syncthreads();
    for (int off = 1; off < 128; off <<= 1) {
        int x = (t >= off) ? sh[t - off] : 0;
        __syncthreads();
        sh[t] += x;
        __syncthreads();
    }
    if (t < nb) bsums[t] = sh[t] - v;
}

// ---------------------------------------------------------------- CSR fill (atomic-free)
__global__ void k_fill(const int* __restrict__ src, const int* __restrict__ dst,
                       const int* __restrict__ offs, const int* __restrict__ bsums,
                       const int* __restrict__ rank, const float* __restrict__ dinv,
                       int2* __restrict__ epack, int E) {
    int e = blockIdx.x * blockDim.x + threadIdx.x;
    if (e < E) {
        int s = src[e], d = dst[e];
        int p = offs[d] + bsums[d >> 10] + rank[e];
        int2 r;
        r.x = s;
        r.y = __float_as_int(dinv[s] * dinv[d]);
        epack[p] = r;
    }
}

// ---------------------------------------------------------------- register-resident MFMA GEMM
// C[M,NOUT] = X[M,K] @ W (+bias), 2-term f16 (W pre-scaled x16, unscaled in
// epilogue). NO LDS, NO BARRIERS. W fragments hoisted to REGISTERS before the
// node loop (R3 post-mortem: inlining W loads in the MFMA loop dropped VGPR
// 136->44 and serialized load->wait->mfma, 25->60us. ILP from NI independent
// node chains + register-resident W beats raw occupancy here).
// NI = 16-node groups per wave; CSPLIT = NOUT/(16*MI) column groups.
template <typename AT, int K, int KPAD, int NI, int MI, int NOUT, bool BIAS, bool F32OUT>
__device__ __forceinline__
void gemm_body(const AT* __restrict__ X,
               const __half* __restrict__ Wh, const __half* __restrict__ Wl,
               const float* __restrict__ bias, void* __restrict__ Cout,
               int M, int orow0, int vb) {
    constexpr int KS = KPAD / 32;
    constexpr int CSPLIT = NOUT / (16 * MI);
    const int tid  = threadIdx.x;
    const int wid  = tid >> 6, lane = tid & 63;
    const int lm   = lane & 15, q = lane >> 4;
    const int gw   = vb * 4 + wid;
    const int tile = gw / CSPLIT;
    const int c0   = (gw % CSPLIT) * (MI * 16);
    const int NT   = (M + NI * 16 - 1) / (NI * 16);
    if (tile >= NT) return;
    const int n0 = tile * (NI * 16);

    half8 wh[MI][KS], wl[MI][KS];
#pragma unroll
    for (int mi = 0; mi < MI; mi++)
#pragma unroll
        for (int ks = 0; ks < KS; ks++) {
            const size_t b = (size_t)(c0 + mi * 16 + lm) * KPAD + ks * 32 + q * 8;
            wh[mi][ks] = *(const half8*)&Wh[b];
            wl[mi][ks] = *(const half8*)&Wl[b];
        }

    f32x4 acc[NI][MI];
#pragma unroll
    for (int ni = 0; ni < NI; ni++)
#pragma unroll
        for (int mi = 0; mi < MI; mi++) acc[ni][mi] = (f32x4)0.0f;

#pragma unroll
    for (int ni = 0; ni < NI; ni++) {
        const int node = n0 + ni * 16 + lm;
        half8 xf[KS];
        if (node < M) {
            if constexpr (sizeof(AT) == 2) {
#pragma unroll
                for (int ks = 0; ks < KS; ks++)
                    xf[ks] = *(const half8*)((const __half*)X + (size_t)node * KPAD + ks * 32 + q * 8);
            } else {
                const float* xp = (const float*)X + (size_t)node * K;
#pragma unroll
                for (int ks = 0; ks < KS; ks++) {
                    const int kb = ks * 32 + q * 8;
                    if (kb + 8 <= K) {
                        float4 v0 = *(const float4*)(xp + kb);
                        float4 v1 = *(const float4*)(xp + kb + 4);
                        xf[ks][0] = (_Float16)v0.x; xf[ks][1] = (_Float16)v0.y;
                        xf[ks][2] = (_Float16)v0.z; xf[ks][3] = (_Float16)v0.w;
                        xf[ks][4] = (_Float16)v1.x; xf[ks][5] = (_Float16)v1.y;
                        xf[ks][6] = (_Float16)v1.z; xf[ks][7] = (_Float16)v1.w;
                    } else if (kb + 4 <= K) {      // K=100 tail: one aligned float4
                        float4 v0 = *(const float4*)(xp + kb);
                        xf[ks][0] = (_Float16)v0.x; xf[ks][1] = (_Float16)v0.y;
                        xf[ks][2] = (_Float16)v0.z; xf[ks][3] = (_Float16)v0.w;
                        xf[ks][4] = (_Float16)0.0f; xf[ks][5] = (_Float16)0.0f;
                        xf[ks][6] = (_Float16)0.0f; xf[ks][7] = (_Float16)0.0f;
                    } else {
#pragma unroll
                        for (int j = 0; j < 8; j++) xf[ks][j] = (_Float16)0.0f;
                    }
                }
            }
        } else {
#pragma unroll
            for (int ks = 0; ks < KS; ks++)
#pragma unroll
                for (int j = 0; j < 8; j++) xf[ks][j] = (_Float16)0.0f;
        }
#pragma unroll
        for (int ks = 0; ks < KS; ks++)
#pragma unroll
            for (int mi = 0; mi < MI; mi++) {
                acc[ni][mi] = __builtin_amdgcn_mfma_f32_16x16x32_f16(wh[mi][ks], xf[ks], acc[ni][mi], 0, 0, 0);
                acc[ni][mi] = __builtin_amdgcn_mfma_f32_16x16x32_f16(wl[mi][ks], xf[ks], acc[ni][mi], 0, 0, 0);
            }
    }

#pragma unroll
    for (int ni = 0; ni < NI; ni++) {
        const int node = n0 + ni * 16 + lm;
        if (node >= M) continue;
#pragma unroll
        for (int mi = 0; mi < MI; mi++) {
            const int cb = c0 + mi * 16 + q * 4;
            float4 bv = BIAS ? *(const float4*)&bias[cb] : make_float4(0.f, 0.f, 0.f, 0.f);
            float v0 = fmaf(acc[ni][mi][0], 0.0625f, bv.x);
            float v1 = fmaf(acc[ni][mi][1], 0.0625f, bv.y);
            float v2 = fmaf(acc[ni][mi][2], 0.0625f, bv.z);
            float v3 = fmaf(acc[ni][mi][3], 0.0625f, bv.w);
            if constexpr (F32OUT) {
                *(float4*)((float*)Cout + (size_t)(orow0 + node) * NOUT + cb) =
                    make_float4(v0, v1, v2, v3);
            } else {
                __half2 h0 = __floats2half2_rn(v0, v1);
                __half2 h1 = __floats2half2_rn(v2, v3);
                uint2 o; o.x = *(unsigned*)&h0; o.y = *(unsigned*)&h1;
                *(uint2*)((__half*)Cout + (size_t)(orow0 + node) * NOUT + cb) = o;
            }
        }
    }
}

template <typename AT, int K, int KPAD, int NI, int MI, int NOUT, bool BIAS, bool F32OUT>
__launch_bounds__(256)
__global__ void k_gemm_reg(const AT* __restrict__ X,
                           const __half* __restrict__ Wh, const __half* __restrict__ Wl,
                           const float* __restrict__ bias, void* __restrict__ Cout,
                           int M, int orow0) {
    gemm_body<AT, K, KPAD, NI, MI, NOUT, BIAS, F32OUT>(X, Wh, Wl, bias, Cout, M, orow0, blockIdx.x);
}

// merged user+prod input transform (one launch, block-range split)
// user: NI=2,MI=4 (3126 waves); prod: NI=2,MI=2 (6252 waves, W frags halved
// so KS=4 doesn't blow the register file). 2-4x the waves of the R2 config
// against the cold 32.8MB fp32 read.
__launch_bounds__(256)
__global__ void k_gemm_inputs(const float* __restrict__ user, const float* __restrict__ prod,
                              const __half* __restrict__ whU, const __half* __restrict__ wlU,
                              const __half* __restrict__ whP, const __half* __restrict__ wlP,
                              const float* __restrict__ bu, const float* __restrict__ bp,
                              void* __restrict__ xA, int blkU) {
    if ((int)blockIdx.x < blkU)
        gemm_body<float,  64,  64, 2, 4, 128, true, false>(user, whU, wlU, bu, xA, NU, 0, blockIdx.x);
    else
        gemm_body<float, 100, 128, 2, 2, 128, true, false>(prod, whP, wlP, bp, xA, NP, NU, blockIdx.x - blkU);
}

// ---------------------------------------------------------------- CSR gather + bias + ReLU
__launch_bounds__(256)
__global__ void k_aggregate(const __half* __restrict__ y, const int* __restrict__ offs,
                            const int* __restrict__ bsums, const int2* __restrict__ epack,
                            const float* __restrict__ dinv, const float* __restrict__ bias,
                            __half* __restrict__ out) {
    const int node = __builtin_amdgcn_readfirstlane(blockIdx.x * 4 + (threadIdx.x >> 6));
    const int l = threadIdx.x & 63;
    const int h = l >> 5, j = l & 31;

    int e0 = offs[node] + bsums[node >> 10];
    int e1 = (node + 1 < NN) ? (offs[node + 1] + bsums[(node + 1) >> 10]) : NE;
    e0 = __builtin_amdgcn_readfirstlane(e0);
    e1 = __builtin_amdgcn_readfirstlane(e1);

    const h4v* y4 = (const h4v*)y;               // row stride = 32 (8B units)

    const float di2 = dinv[node] * dinv[node];
    h4v sv = y4[(size_t)node * 32 + j];
    float4 bv = *(const float4*)&bias[4 * j];

    f32x4 acc0 = (f32x4)0.f, acc1 = (f32x4)0.f, acc2 = (f32x4)0.f, acc3 = (f32x4)0.f;

    for (int e = e0; e < e1; e += 8) {
        const int eb = e + 4 * h;
        const int2* pe = epack + eb;
        int2 p0 = pe[0];                          // contiguous 32B per half
        int2 p1 = pe[1];
        int2 p2 = pe[2];
        int2 p3 = pe[3];
        float w0 = (eb + 0 < e1) ? __int_as_float(p0.y) : 0.f;
        float w1 = (eb + 1 < e1) ? __int_as_float(p1.y) : 0.f;
        float w2 = (eb + 2 < e1) ? __int_as_float(p2.y) : 0.f;
        float w3 = (eb + 3 < e1) ? __int_as_float(p3.y) : 0.f;
        h4v v0 = y4[(size_t)p0.x * 32 + j];      // 2 rows per gather instr
        h4v v1 = y4[(size_t)p1.x * 32 + j];
        h4v v2 = y4[(size_t)p2.x * 32 + j];
        h4v v3 = y4[(size_t)p3.x * 32 + j];
        acc0[0] = fmaf((float)v0[0], w0, acc0[0]); acc0[1] = fmaf((float)v0[1], w0, acc0[1]);
        acc0[2] = fmaf((float)v0[2], w0, acc0[2]); acc0[3] = fmaf((float)v0[3], w0, acc0[3]);
        acc1[0] = fmaf((float)v1[0], w1, acc1[0]); acc1[1] = fmaf((float)v1[1], w1, acc1[1]);
        acc1[2] = fmaf((float)v1[2], w1, acc1[2]); acc1[3] = fmaf((float)v1[3], w1, acc1[3]);
        acc2[0] = fmaf((float)v2[0], w2, acc2[0]); acc2[1] = fmaf((float)v2[1], w2, acc2[1]);
        acc2[2] = fmaf((float)v2[2], w2, acc2[2]); acc2[3] = fmaf((float)v2[3], w2, acc2[3]);
        acc3[0] = fmaf((float)v3[0], w3, acc3[0]); acc3[1] = fmaf((float)v3[1], w3, acc3[1]);
        acc3[2] = fmaf((float)v3[2], w3, acc3[2]); acc3[3] = fmaf((float)v3[3], w3, acc3[3]);
    }

    f32x4 s = (acc0 + acc1) + (acc2 + acc3);
    float t0 = s[0] + __shfl_xor(s[0], 32, 64);
    float t1 = s[1] + __shfl_xor(s[1], 32, 64);
    float t2 = s[2] + __shfl_xor(s[2], 32, 64);
    float t3 = s[3] + __shfl_xor(s[3], 32, 64);

    float r0 = fmaf((float)sv[0], di2, t0) + bv.x;
    float r1 = fmaf((float)sv[1], di2, t1) + bv.y;
    float r2 = fmaf((float)sv[2], di2, t2) + bv.z;
    float r3 = fmaf((float)sv[3], di2, t3) + bv.w;
    if (l < 32) {
        __half2 ha = __floats2half2_rn(fmaxf(r0, 0.f), fmaxf(r1, 0.f));
        __half2 hb = __floats2half2_rn(fmaxf(r2, 0.f), fmaxf(r3, 0.f));
        uint2 o; o.x = *(unsigned*)&ha; o.y = *(unsigned*)&hb;
        *(uint2*)(out + (size_t)node * H + 4 * j) = o;
    }
}

// ---------------------------------------------------------------- launch
extern "C" void kernel_launch(void* const* d_in, const int* in_sizes, int n_in,
                              void* d_out, int out_size, void* d_ws, size_t ws_size,
                              hipStream_t stream) {
    const float* user = (const float*)d_in[0];
    const float* prod = (const float*)d_in[1];
    const int*   eidx = (const int*)  d_in[2];
    const int*   edst = eidx + NE;
    const int*   esrc = eidx;
    const float* Wu = (const float*)d_in[3];
    const float* bu = (const float*)d_in[4];
    const float* Wp = (const float*)d_in[5];
    const float* bp = (const float*)d_in[6];
    const float* W1 = (const float*)d_in[7];
    const float* b1 = (const float*)d_in[8];
    const float* W2 = (const float*)d_in[9];
    const float* b2 = (const float*)d_in[10];
    const float* W3 = (const float*)d_in[11];
    const float* b3 = (const float*)d_in[12];
    const float* Wo = (const float*)d_in[13];
    const float* bo = (const float*)d_in[14];
    float* out = (float*)d_out;

    char* ws = (char*)d_ws;
    size_t p = 0;
    auto alloc = [&](size_t bytes) -> void* {
        void* r = ws + p;
        p += (bytes + 255) & ~(size_t)255;
        return r;
    };
    __half* xA   = (__half*)alloc((size_t)NN * H * 2);
    __half* xB   = (__half*)alloc((size_t)NN * H * 2);
    int*   cnt   = (int*)  alloc((size_t)NN * 4);
    int*   rank  = (int*)  alloc((size_t)NE * 4);
    int*   offs  = (int*)  alloc((size_t)(NN + 1) * 4);
    float* dinv  = (float*)alloc((size_t)NN * 4);
    int2*  epack = (int2*) alloc((size_t)(NE + 8) * 8);
    int*   bsums = (int*)  alloc(128 * 4);
    __half* whU = (__half*)alloc(128 * 64 * 2);
    __half* wlU = (__half*)alloc(128 * 64 * 2);
    __half* whP = (__half*)alloc(128 * 128 * 2);
    __half* wlP = (__half*)alloc(128 * 128 * 2);
    __half* wh1 = (__half*)alloc(128 * 128 * 2);
    __half* wl1 = (__half*)alloc(128 * 128 * 2);
    __half* wh2 = (__half*)alloc(128 * 128 * 2);
    __half* wl2 = (__half*)alloc(128 * 128 * 2);
    __half* wh3 = (__half*)alloc(128 * 128 * 2);
    __half* wl3 = (__half*)alloc(128 * 128 * 2);
    __half* whO = (__half*)alloc(16 * 128 * 2);
    __half* wlO = (__half*)alloc(16 * 128 * 2);

    const int NBLK = (NN + SCAN_CHUNK - 1) / SCAN_CHUNK;   // 98

    // weight prep + cnt zero + epack pad (one launch)
    k_prep<<<(75776 + NN + 8 + 255) / 256, 256, 0, stream>>>(
        Wu, Wp, W1, W2, W3, Wo,
        whU, wlU, whP, wlP, wh1, wl1, wh2, wl2, wh3, wl3, whO, wlO, cnt, epack);

    // graph structure
    k_count<<<(NE + 255) / 256, 256, 0, stream>>>(edst, cnt, rank, NE);
    k_scan1<<<NBLK, SCAN_TPB, 0, stream>>>(cnt, offs, bsums, dinv, NN);
    k_scan2<<<1, 128, 0, stream>>>(bsums, NBLK);
    k_fill <<<(NE + 255) / 256, 256, 0, stream>>>(esrc, edst, offs, bsums, rank, dinv,
                                                  epack, NE);

    // input feature transforms -> xA (fp16), merged into one launch
    {
        // user: NT=ceil(50000/32)=1563, CSPLIT=2 -> 3126 waves -> 782 blocks
        // prod: NT=1563, CSPLIT=4 -> 6252 waves -> 1563 blocks
        constexpr int blkU = (1563 * 2 + 3) / 4;   // 782
        constexpr int blkP = (1563 * 4 + 3) / 4;   // 1563
        k_gemm_inputs<<<blkU + blkP, 256, 0, stream>>>(
            user, prod, whU, wlU, whP, wlP, bu, bp, xA, blkU);
    }

    // hidden gemms: NT=ceil(100000/64)=1563, CSPLIT=2 -> 3126 waves -> 782 blocks
    const int blkG = (1563 * 2 + 3) / 4;   // 782
    // head: NT=1563, CSPLIT=1 -> 1563 waves -> 391 blocks
    const int blkO = (1563 + 3) / 4;       // 391

    // layer 1
    k_gemm_reg<__half, 128, 128, 4, 4, 128, false, false><<<blkG, 256, 0, stream>>>(xA, wh1, wl1, nullptr, xB, NN, 0);
    k_aggregate<<<NN / 4, 256, 0, stream>>>(xB, offs, bsums, epack, dinv, b1, xA);
    // layer 2
    k_gemm_reg<__half, 128, 128, 4, 4, 128, false, false><<<blkG, 256, 0, stream>>>(xA, wh2, wl2, nullptr, xB, NN, 0);
    k_aggregate<<<NN / 4, 256, 0, stream>>>(xB, offs, bsums, epack, dinv, b2, xA);
    // layer 3
    k_gemm_reg<__half, 128, 128, 4, 4, 128, false, false><<<blkG, 256, 0, stream>>>(xA, wh3, wl3, nullptr, xB, NN, 0);
    k_aggregate<<<NN / 4, 256, 0, stream>>>(xB, offs, bsums, epack, dinv, b3, xA);

    // output head [NN,128] @ [128,16] + bo -> fp32 out
    k_gemm_reg<__half, 128, 128, 4, 1, 16, true, true><<<blkO, 256, 0, stream>>>(xA, whO, wlO, bo, out, NN, 0);
}